// Round 1
// baseline (798.047 us; speedup 1.0000x reference)
//
#include <hip/hip_runtime.h>

typedef unsigned short u16;
typedef __attribute__((ext_vector_type(4))) float  f32x4;
typedef __attribute__((ext_vector_type(4))) float  float4v;
typedef __attribute__((ext_vector_type(4))) unsigned short u16x4;
typedef __attribute__((ext_vector_type(8))) unsigned short u16x8;
typedef __attribute__((ext_vector_type(8))) short s16x8;

#define SEQ 4096
#define DA  2048
#define NH  16
#define DKV 128

__device__ __forceinline__ u16 f2bf(float f) {
    unsigned u = __builtin_bit_cast(unsigned, f);
    u += 0x7FFFu + ((u >> 16) & 1u);           // round-nearest-even
    return (u16)(u >> 16);
}
__device__ __forceinline__ float bf2f(u16 h) {
    return __builtin_bit_cast(float, (unsigned)h << 16);
}
__device__ __forceinline__ f32x4 mfma16(u16x8 a, u16x8 b, f32x4 c) {
    return __builtin_amdgcn_mfma_f32_16x16x32_bf16(
        __builtin_bit_cast(s16x8, a), __builtin_bit_cast(s16x8, b), c, 0, 0, 0);
}
// swizzled LDS addressing: XOR row-low-bits into byte-bit-4 (16B granule)
__device__ __forceinline__ char* ldsp(void* base, int row, int bcol, int rowbytes) {
    int off = row * rowbytes + bcol;
    off ^= (row & 7) << 4;
    return (char*)base + off;
}

// ---------------------------------------------------------------------------
// Transpose + split-convert: in f32 [B][R][C] -> oh/ol bf16 [B][C][R]
// ---------------------------------------------------------------------------
__global__ void transpose_split_k(const float* __restrict__ in, u16* __restrict__ oh,
                                  u16* __restrict__ ol, int R, int C) {
    __shared__ float tile[32][33];
    int b  = blockIdx.z;
    int r0 = blockIdx.x * 32, c0 = blockIdx.y * 32;
    const float* src = in + (size_t)b * R * C;
    int t = threadIdx.x;
    {
        int cl = t & 31, r = t >> 5;
        for (int i = 0; i < 4; ++i)
            tile[r + 8 * i][cl] = src[(size_t)(r0 + r + 8 * i) * C + (c0 + cl)];
    }
    __syncthreads();
    int rl = t & 31, c = t >> 5;
    size_t obase = (size_t)b * R * C;
    for (int i = 0; i < 4; ++i) {
        int cw = c + 8 * i;
        float x = tile[rl][cw];
        u16 h = f2bf(x);
        size_t o = obase + (size_t)(c0 + cw) * R + (r0 + rl);
        oh[o] = h;
        if (ol) ol[o] = f2bf(x - bf2f(h));
    }
}

// ---------------------------------------------------------------------------
// Projection GEMM: C[h][s][n] = sum_k A[s][k] * E[h][k][n]
// A: f32 [SEQ][DA] (split to hi/lo in staging). BT: bf16 [h][128][2048] (hi[,lo]).
// MODE 0: V -> write bf16 transposed VT[h][v][s] (hi only, 1 MFMA/pair)
// MODE 1: K -> split bf16 Oh/Ol, layout [h][s][128]   (3 MFMA/pair)
// MODE 2: Q -> like K, times scale 1/128
// Tile 128x128, BK=64, 256 threads (4 waves as 2x2, each 64x64).
// ---------------------------------------------------------------------------
template <int MODE>
__global__ void __launch_bounds__(256) proj_k(const float* __restrict__ A,
                                              const u16* __restrict__ BTh,
                                              const u16* __restrict__ BTl,
                                              u16* __restrict__ Oh,
                                              u16* __restrict__ Ol) {
    __shared__ u16 sAh[128 * 64];
    __shared__ u16 sBh[128 * 64];
    __shared__ u16 sAl[MODE ? 128 * 64 : 8];
    __shared__ u16 sBl[MODE ? 128 * 64 : 8];

    int t = threadIdx.x;
    int h = blockIdx.y;
    int bm0 = blockIdx.x * 128;
    int lane = t & 63, w = t >> 6, wr = w >> 1, wc = w & 1;
    int g = lane >> 4, c = lane & 15;

    f32x4 acc[4][4] = {};

    for (int k0 = 0; k0 < DA; k0 += 64) {
        __syncthreads();
        // stage A (f32 -> hi/lo bf16), 128x64
        for (int i = 0; i < 8; ++i) {
            int idx = t + i * 256;               // 0..2047 float4s
            int row = idx >> 4, c4 = idx & 15;
            float4v av = *(const float4v*)(A + (size_t)(bm0 + row) * DA + k0 + c4 * 4);
            u16x4 hv, lv;
            for (int j = 0; j < 4; ++j) {
                u16 hh = f2bf(av[j]);
                hv[j] = hh;
                lv[j] = f2bf(av[j] - bf2f(hh));
            }
            *(u16x4*)ldsp(sAh, row, c4 * 8, 128) = hv;
            if (MODE) *(u16x4*)ldsp(sAl, row, c4 * 8, 128) = lv;
        }
        // stage B (already bf16), [n][k] 128x64
        for (int i = 0; i < 4; ++i) {
            int idx = t + i * 256;               // 0..1023
            int row = idx >> 3, c8 = idx & 7;
            size_t gb = ((size_t)h * 128 + row) * DA + k0 + c8 * 8;
            *(u16x8*)ldsp(sBh, row, c8 * 16, 128) = *(const u16x8*)(BTh + gb);
            if (MODE) *(u16x8*)ldsp(sBl, row, c8 * 16, 128) = *(const u16x8*)(BTl + gb);
        }
        __syncthreads();

        for (int kc = 0; kc < 2; ++kc) {
            int kb = (kc * 32 + g * 8) * 2;      // byte column
            u16x8 ah[4], al[4], bh[4], bl[4];
            for (int m = 0; m < 4; ++m) {
                int row = wr * 64 + m * 16 + c;
                ah[m] = *(u16x8*)ldsp(sAh, row, kb, 128);
                if (MODE) al[m] = *(u16x8*)ldsp(sAl, row, kb, 128);
            }
            for (int n = 0; n < 4; ++n) {
                int row = wc * 64 + n * 16 + c;
                bh[n] = *(u16x8*)ldsp(sBh, row, kb, 128);
                if (MODE) bl[n] = *(u16x8*)ldsp(sBl, row, kb, 128);
            }
            for (int m = 0; m < 4; ++m)
                for (int n = 0; n < 4; ++n) {
                    acc[m][n] = mfma16(ah[m], bh[n], acc[m][n]);
                    if (MODE) {
                        acc[m][n] = mfma16(ah[m], bl[n], acc[m][n]);
                        acc[m][n] = mfma16(al[m], bh[n], acc[m][n]);
                    }
                }
        }
    }

    const float scale = (MODE == 2) ? (1.0f / 128.0f) : 1.0f;
    for (int m = 0; m < 4; ++m)
        for (int n = 0; n < 4; ++n) {
            int col  = wc * 64 + n * 16 + c;
            int row0 = bm0 + wr * 64 + m * 16 + g * 4;
            if (MODE == 0) {
                u16x4 pv;
                for (int j = 0; j < 4; ++j) pv[j] = f2bf(acc[m][n][j]);
                *(u16x4*)(Oh + ((size_t)h * DKV + col) * SEQ + row0) = pv;
            } else {
                for (int j = 0; j < 4; ++j) {
                    float v = acc[m][n][j] * scale;
                    u16 hh = f2bf(v);
                    size_t o = ((size_t)h * SEQ + row0 + j) * DKV + col;
                    Oh[o] = hh;
                    Ol[o] = f2bf(v - bf2f(hh));
                }
            }
        }
}

// ---------------------------------------------------------------------------
// Flash attention: per (head, 128 q-rows). 8 waves, each owns 16 q-rows.
// QH/QL,KH/KL: split bf16 [h][s][128] (Q pre-scaled by 1/128). VT: bf16 [h][v][s].
// Writes Abuf bf16 [s][h*128+v].
// ---------------------------------------------------------------------------
__global__ void __launch_bounds__(512) attn_k(const u16* __restrict__ QH,
                                              const u16* __restrict__ QL,
                                              const u16* __restrict__ KH,
                                              const u16* __restrict__ KL,
                                              const u16* __restrict__ VT,
                                              u16* __restrict__ Abuf) {
    __shared__ u16 sKh[64 * 128];
    __shared__ u16 sKl[64 * 128];
    __shared__ u16 sVT[128 * 64];
    __shared__ u16 sP[8 * 16 * 64];

    int t = threadIdx.x, lane = t & 63, w = t >> 6;
    int h = blockIdx.y, q0 = blockIdx.x * 128;
    int g = lane >> 4, c = lane & 15;

    // Q fragments in registers (hi+lo), rows q0 + w*16 + c
    u16x8 qh[4], ql[4];
    {
        size_t base = ((size_t)h * SEQ + q0 + w * 16 + c) * DKV;
        for (int kc = 0; kc < 4; ++kc) {
            qh[kc] = *(const u16x8*)(QH + base + kc * 32 + g * 8);
            ql[kc] = *(const u16x8*)(QL + base + kc * 32 + g * 8);
        }
    }

    f32x4 o[8] = {};
    float mrun[4] = {-3e38f, -3e38f, -3e38f, -3e38f};
    float lrun[4] = {0.f, 0.f, 0.f, 0.f};

    for (int kv0 = 0; kv0 < SEQ; kv0 += 64) {
        __syncthreads();
        // stage K hi/lo 64x128 (rows 256B, swizzled)
        for (int i = 0; i < 2; ++i) {
            int idx = t + i * 512;               // 0..1023
            int row = idx >> 4, c8 = idx & 15;
            size_t gb = ((size_t)h * SEQ + kv0 + row) * DKV + c8 * 8;
            *(u16x8*)ldsp(sKh, row, c8 * 16, 256) = *(const u16x8*)(KH + gb);
            *(u16x8*)ldsp(sKl, row, c8 * 16, 256) = *(const u16x8*)(KL + gb);
        }
        // stage V^T 128x64 (rows 128B, swizzled)
        for (int i = 0; i < 2; ++i) {
            int idx = t + i * 512;               // 0..1023
            int row = idx >> 3, c8 = idx & 7;
            *(u16x8*)ldsp(sVT, row, c8 * 16, 128) =
                *(const u16x8*)(VT + ((size_t)h * DKV + row) * SEQ + kv0 + c8 * 8);
        }
        __syncthreads();

        // S = Qs * K^T  (split: 3 MFMAs per pair), 16 q-rows x 64 kv
        f32x4 s[4] = {};
        for (int ct = 0; ct < 4; ++ct)
            for (int kc = 0; kc < 4; ++kc) {
                int kb = (kc * 32 + g * 8) * 2;
                u16x8 kh = *(u16x8*)ldsp(sKh, ct * 16 + c, kb, 256);
                u16x8 kl = *(u16x8*)ldsp(sKl, ct * 16 + c, kb, 256);
                s[ct] = mfma16(qh[kc], kh, s[ct]);
                s[ct] = mfma16(qh[kc], kl, s[ct]);
                s[ct] = mfma16(ql[kc], kh, s[ct]);
            }

        // online softmax: rows g*4+j live across the 16 lanes with same g
        float corr[4];
        for (int j = 0; j < 4; ++j) {
            float v = fmaxf(fmaxf(s[0][j], s[1][j]), fmaxf(s[2][j], s[3][j]));
            for (int msk = 1; msk < 16; msk <<= 1) v = fmaxf(v, __shfl_xor(v, msk));
            float mnew = fmaxf(mrun[j], v);
            corr[j] = __expf(mrun[j] - mnew);
            mrun[j] = mnew;
        }
        float rs[4] = {0.f, 0.f, 0.f, 0.f};
        for (int ct = 0; ct < 4; ++ct)
            for (int j = 0; j < 4; ++j) {
                float p = __expf(s[ct][j] - mrun[j]);
                s[ct][j] = p;
                rs[j] += p;
            }
        for (int j = 0; j < 4; ++j) {
            for (int msk = 1; msk < 16; msk <<= 1) rs[j] += __shfl_xor(rs[j], msk);
            lrun[j] = lrun[j] * corr[j] + rs[j];
        }
        for (int vt = 0; vt < 8; ++vt)
            for (int j = 0; j < 4; ++j) o[vt][j] *= corr[j];

        // P -> LDS (per-wave region), C-layout scatter, swizzled
        u16* pb = sP + w * (16 * 64);
        for (int ct = 0; ct < 4; ++ct)
            for (int j = 0; j < 4; ++j)
                *(u16*)ldsp(pb, g * 4 + j, (ct * 16 + c) * 2, 128) = f2bf(s[ct][j]);
        __syncthreads();   // order P writes (cross-lane) before A-frag reads

        // O += P * V
        for (int kc2 = 0; kc2 < 2; ++kc2) {
            int kb = (kc2 * 32 + g * 8) * 2;
            u16x8 pf = *(u16x8*)ldsp(pb, c, kb, 128);
            for (int vt = 0; vt < 8; ++vt) {
                u16x8 vf = *(u16x8*)ldsp(sVT, vt * 16 + c, kb, 128);
                o[vt] = mfma16(pf, vf, o[vt]);
            }
        }
    }

    for (int j = 0; j < 4; ++j) lrun[j] = 1.0f / lrun[j];
    int srow = q0 + w * 16 + g * 4;
    for (int vt = 0; vt < 8; ++vt)
        for (int j = 0; j < 4; ++j)
            Abuf[(size_t)(srow + j) * (NH * DKV) + h * DKV + vt * 16 + c] =
                f2bf(o[vt][j] * lrun[j]);
}

// ---------------------------------------------------------------------------
// Final GEMM: out f32 [SEQ][DA] = Abuf bf16 [SEQ][2048] @ W (via WT bf16 [d][j])
// ---------------------------------------------------------------------------
__global__ void __launch_bounds__(256) gemm_out_k(const u16* __restrict__ Abuf,
                                                  const u16* __restrict__ WT,
                                                  float* __restrict__ out) {
    __shared__ u16 sA[128 * 64];
    __shared__ u16 sB[128 * 64];
    int t = threadIdx.x, lane = t & 63, w = t >> 6, wr = w >> 1, wc = w & 1;
    int g = lane >> 4, c = lane & 15;
    int bm0 = blockIdx.x * 128, bn0 = blockIdx.y * 128;
    f32x4 acc[4][4] = {};

    for (int k0 = 0; k0 < DA; k0 += 64) {
        __syncthreads();
        for (int i = 0; i < 4; ++i) {
            int idx = t + i * 256, row = idx >> 3, c8 = idx & 7;
            *(u16x8*)ldsp(sA, row, c8 * 16, 128) =
                *(const u16x8*)(Abuf + (size_t)(bm0 + row) * DA + k0 + c8 * 8);
            *(u16x8*)ldsp(sB, row, c8 * 16, 128) =
                *(const u16x8*)(WT + (size_t)(bn0 + row) * DA + k0 + c8 * 8);
        }
        __syncthreads();
        for (int kc = 0; kc < 2; ++kc) {
            int kb = (kc * 32 + g * 8) * 2;
            u16x8 af[4], bfq[4];
            for (int m = 0; m < 4; ++m) af[m]  = *(u16x8*)ldsp(sA, wr * 64 + m * 16 + c, kb, 128);
            for (int n = 0; n < 4; ++n) bfq[n] = *(u16x8*)ldsp(sB, wc * 64 + n * 16 + c, kb, 128);
            for (int m = 0; m < 4; ++m)
                for (int n = 0; n < 4; ++n)
                    acc[m][n] = mfma16(af[m], bfq[n], acc[m][n]);
        }
    }
    for (int m = 0; m < 4; ++m)
        for (int n = 0; n < 4; ++n) {
            int row0 = bm0 + wr * 64 + m * 16 + g * 4;
            int col  = bn0 + wc * 64 + n * 16 + c;
            for (int j = 0; j < 4; ++j)
                out[(size_t)(row0 + j) * DA + col] = acc[m][n][j];
        }
}

// ---------------------------------------------------------------------------
extern "C" void kernel_launch(void* const* d_in, const int* in_sizes, int n_in,
                              void* d_out, int out_size, void* d_ws, size_t ws_size,
                              hipStream_t stream) {
    const float* queries = (const float*)d_in[0];
    const float* keys    = (const float*)d_in[1];
    const float* values  = (const float*)d_in[2];
    const float* Eq      = (const float*)d_in[3];
    const float* Ek      = (const float*)d_in[4];
    const float* Ev      = (const float*)d_in[5];
    const float* Wout    = (const float*)d_in[6];
    float* out = (float*)d_out;

    const size_t PROJ = (size_t)NH * SEQ * DKV;   // 8,388,608 elems
    const size_t TSZ  = (size_t)DA * DA;          // 4,194,304 elems (== 16*128*2048)
    u16* p  = (u16*)d_ws;
    u16* QH = p; p += PROJ;
    u16* QL = p; p += PROJ;
    u16* KH = p; p += PROJ;
    u16* KL = p; p += PROJ;
    u16* VT = p; p += PROJ;
    u16* AB = p; p += (size_t)SEQ * NH * DKV;
    u16* TH = p; p += TSZ;
    u16* TL = p; p += TSZ;

    dim3 tgE(DA / 32, DKV / 32, NH);   // E transposes
    dim3 tgW(DA / 32, DA / 32, 1);     // W transpose
    dim3 pg(SEQ / 128, NH);

    // Q chain
    transpose_split_k<<<tgE, 256, 0, stream>>>(Eq, TH, TL, DA, DKV);
    proj_k<2><<<pg, 256, 0, stream>>>(queries, TH, TL, QH, QL);
    // K chain
    transpose_split_k<<<tgE, 256, 0, stream>>>(Ek, TH, TL, DA, DKV);
    proj_k<1><<<pg, 256, 0, stream>>>(keys, TH, TL, KH, KL);
    // V chain (hi only, output transposed)
    transpose_split_k<<<tgE, 256, 0, stream>>>(Ev, TH, nullptr, DA, DKV);
    proj_k<0><<<pg, 256, 0, stream>>>(values, TH, nullptr, VT, nullptr);
    // W transpose (hi only)
    transpose_split_k<<<tgW, 256, 0, stream>>>(Wout, TH, nullptr, DA, DA);
    // attention
    attn_k<<<dim3(SEQ / 128, NH), 512, 0, stream>>>(QH, QL, KH, KL, VT, AB);
    // output projection
    gemm_out_k<<<dim3(SEQ / 128, DA / 128), 256, 0, stream>>>(AB, TH, out);
}

// Round 2
// 675.369 us; speedup vs baseline: 1.1816x; 1.1816x over previous
//
#include <hip/hip_runtime.h>

typedef unsigned short u16;
typedef __attribute__((ext_vector_type(4)))  float  f32x4;
typedef __attribute__((ext_vector_type(16))) float  f32x16;
typedef __attribute__((ext_vector_type(4)))  float  float4v;
typedef __attribute__((ext_vector_type(4)))  unsigned short u16x4;
typedef __attribute__((ext_vector_type(8)))  unsigned short u16x8;
typedef __attribute__((ext_vector_type(8)))  short s16x8;
typedef __attribute__((ext_vector_type(4)))  unsigned int u32x4;

#define SEQ 4096
#define DA  2048
#define NH  16
#define DKV 128

__device__ __forceinline__ u16 f2bf(float f) {
    unsigned u = __builtin_bit_cast(unsigned, f);
    u += 0x7FFFu + ((u >> 16) & 1u);           // round-nearest-even
    return (u16)(u >> 16);
}
__device__ __forceinline__ float bf2f(u16 h) {
    return __builtin_bit_cast(float, (unsigned)h << 16);
}
__device__ __forceinline__ f32x4 mfma16(u16x8 a, u16x8 b, f32x4 c) {
    return __builtin_amdgcn_mfma_f32_16x16x32_bf16(
        __builtin_bit_cast(s16x8, a), __builtin_bit_cast(s16x8, b), c, 0, 0, 0);
}
__device__ __forceinline__ f32x16 mfma32(u16x8 a, u16x8 b, f32x16 c) {
    return __builtin_amdgcn_mfma_f32_32x32x16_bf16(
        __builtin_bit_cast(s16x8, a), __builtin_bit_cast(s16x8, b), c, 0, 0, 0);
}
__device__ __forceinline__ unsigned cvtpk(float lo, float hi) {
    unsigned r;
    asm("v_cvt_pk_bf16_f32 %0, %1, %2" : "=v"(r) : "v"(lo), "v"(hi));
    return r;
}
// swizzled LDS addressing: XOR row-low-bits into byte-bit-4 (16B granule)
__device__ __forceinline__ char* ldsp(void* base, int row, int bcol, int rowbytes) {
    int off = row * rowbytes + bcol;
    off ^= (row & 7) << 4;
    return (char*)base + off;
}

// ---------------------------------------------------------------------------
// Transpose + split-convert: in f32 [B][R][C] -> oh/ol bf16 [B][C][R]
// ---------------------------------------------------------------------------
__global__ void transpose_split_k(const float* __restrict__ in, u16* __restrict__ oh,
                                  u16* __restrict__ ol, int R, int C) {
    __shared__ float tile[32][33];
    int b  = blockIdx.z;
    int r0 = blockIdx.x * 32, c0 = blockIdx.y * 32;
    const float* src = in + (size_t)b * R * C;
    int t = threadIdx.x;
    {
        int cl = t & 31, r = t >> 5;
        for (int i = 0; i < 4; ++i)
            tile[r + 8 * i][cl] = src[(size_t)(r0 + r + 8 * i) * C + (c0 + cl)];
    }
    __syncthreads();
    int rl = t & 31, c = t >> 5;
    size_t obase = (size_t)b * R * C;
    for (int i = 0; i < 4; ++i) {
        int cw = c + 8 * i;
        float x = tile[rl][cw];
        u16 h = f2bf(x);
        size_t o = obase + (size_t)(c0 + cw) * R + (r0 + rl);
        oh[o] = h;
        if (ol) ol[o] = f2bf(x - bf2f(h));
    }
}

// ---------------------------------------------------------------------------
// Projection GEMM: C[h][s][n] = sum_k A[s][k] * E[h][k][n]
// MODE 0: V -> bf16 transposed VT[h][v][s] (hi only). MODE 1: K split. MODE 2: Q split*1/128.
// ---------------------------------------------------------------------------
template <int MODE>
__global__ void __launch_bounds__(256) proj_k(const float* __restrict__ A,
                                              const u16* __restrict__ BTh,
                                              const u16* __restrict__ BTl,
                                              u16* __restrict__ Oh,
                                              u16* __restrict__ Ol) {
    __shared__ u16 sAh[128 * 64];
    __shared__ u16 sBh[128 * 64];
    __shared__ u16 sAl[MODE ? 128 * 64 : 8];
    __shared__ u16 sBl[MODE ? 128 * 64 : 8];

    int t = threadIdx.x;
    int h = blockIdx.y;
    int bm0 = blockIdx.x * 128;
    int lane = t & 63, w = t >> 6, wr = w >> 1, wc = w & 1;
    int g = lane >> 4, c = lane & 15;

    f32x4 acc[4][4] = {};

    for (int k0 = 0; k0 < DA; k0 += 64) {
        __syncthreads();
        for (int i = 0; i < 8; ++i) {
            int idx = t + i * 256;               // 0..2047 float4s
            int row = idx >> 4, c4 = idx & 15;
            float4v av = *(const float4v*)(A + (size_t)(bm0 + row) * DA + k0 + c4 * 4);
            u16x4 hv, lv;
            for (int j = 0; j < 4; ++j) {
                u16 hh = f2bf(av[j]);
                hv[j] = hh;
                lv[j] = f2bf(av[j] - bf2f(hh));
            }
            *(u16x4*)ldsp(sAh, row, c4 * 8, 128) = hv;
            if (MODE) *(u16x4*)ldsp(sAl, row, c4 * 8, 128) = lv;
        }
        for (int i = 0; i < 4; ++i) {
            int idx = t + i * 256;               // 0..1023
            int row = idx >> 3, c8 = idx & 7;
            size_t gb = ((size_t)h * 128 + row) * DA + k0 + c8 * 8;
            *(u16x8*)ldsp(sBh, row, c8 * 16, 128) = *(const u16x8*)(BTh + gb);
            if (MODE) *(u16x8*)ldsp(sBl, row, c8 * 16, 128) = *(const u16x8*)(BTl + gb);
        }
        __syncthreads();

        for (int kc = 0; kc < 2; ++kc) {
            int kb = (kc * 32 + g * 8) * 2;      // byte column
            u16x8 ah[4], al[4], bh[4], bl[4];
            for (int m = 0; m < 4; ++m) {
                int row = wr * 64 + m * 16 + c;
                ah[m] = *(u16x8*)ldsp(sAh, row, kb, 128);
                if (MODE) al[m] = *(u16x8*)ldsp(sAl, row, kb, 128);
            }
            for (int n = 0; n < 4; ++n) {
                int row = wc * 64 + n * 16 + c;
                bh[n] = *(u16x8*)ldsp(sBh, row, kb, 128);
                if (MODE) bl[n] = *(u16x8*)ldsp(sBl, row, kb, 128);
            }
            for (int m = 0; m < 4; ++m)
                for (int n = 0; n < 4; ++n) {
                    acc[m][n] = mfma16(ah[m], bh[n], acc[m][n]);
                    if (MODE) {
                        acc[m][n] = mfma16(ah[m], bl[n], acc[m][n]);
                        acc[m][n] = mfma16(al[m], bh[n], acc[m][n]);
                    }
                }
        }
    }

    const float scale = (MODE == 2) ? (1.0f / 128.0f) : 1.0f;
    for (int m = 0; m < 4; ++m)
        for (int n = 0; n < 4; ++n) {
            int col  = wc * 64 + n * 16 + c;
            int row0 = bm0 + wr * 64 + m * 16 + g * 4;
            if (MODE == 0) {
                u16x4 pv;
                for (int j = 0; j < 4; ++j) pv[j] = f2bf(acc[m][n][j]);
                *(u16x4*)(Oh + ((size_t)h * DKV + col) * SEQ + row0) = pv;
            } else {
                for (int j = 0; j < 4; ++j) {
                    float v = acc[m][n][j] * scale;
                    u16 hh = f2bf(v);
                    size_t o = ((size_t)h * SEQ + row0 + j) * DKV + col;
                    Oh[o] = hh;
                    Ol[o] = f2bf(v - bf2f(hh));
                }
            }
        }
}

// ---------------------------------------------------------------------------
// Flash attention v2: 32x32x16 MFMA, swapped QK^T (A=K, B=Q) -> lane owns one
// q-row; in-register softmax + cvt_pk/shfl P-conversion; PV computes
// O^T = V^T · P^T with V^T as A-frag. 4 waves x 32 q-rows = 128 q/block.
// ---------------------------------------------------------------------------
__global__ void __launch_bounds__(256, 2) attn_k(const u16* __restrict__ QH,
                                                 const u16* __restrict__ QL,
                                                 const u16* __restrict__ KH,
                                                 const u16* __restrict__ KL,
                                                 const u16* __restrict__ VT,
                                                 u16* __restrict__ Abuf) {
    __shared__ u16 sKh[64 * 128];
    __shared__ u16 sKl[64 * 128];
    __shared__ u16 sV[128 * 64];

    int t = threadIdx.x, lane = t & 63, w = t >> 6;
    int h = blockIdx.y, q0 = blockIdx.x * 128;
    int c = lane & 31, hi = lane >> 5;
    int qrow = q0 + w * 32 + c;

    // Q fragments (B-operand layout): lane holds Q[qrow][dc*16 + hi*8 .. +7]
    u16x8 qh[8], ql[8];
    {
        size_t base = ((size_t)h * SEQ + qrow) * DKV + hi * 8;
#pragma unroll
        for (int dc = 0; dc < 8; ++dc) {
            qh[dc] = *(const u16x8*)(QH + base + dc * 16);
            ql[dc] = *(const u16x8*)(QL + base + dc * 16);
        }
    }

    f32x16 o[4] = {};
    float mrun = -3e38f, lrun = 0.f;

    for (int kv0 = 0; kv0 < SEQ; kv0 += 64) {
        __syncthreads();
#pragma unroll
        for (int i = 0; i < 4; ++i) {
            int idx = t + i * 256;
            {
                int row = idx >> 4, c8 = idx & 15;
                size_t gb = ((size_t)h * SEQ + kv0 + row) * DKV + c8 * 8;
                *(u16x8*)ldsp(sKh, row, c8 * 16, 256) = *(const u16x8*)(KH + gb);
                *(u16x8*)ldsp(sKl, row, c8 * 16, 256) = *(const u16x8*)(KL + gb);
            }
            {
                int row = idx >> 3, c8 = idx & 7;
                *(u16x8*)ldsp(sV, row, c8 * 16, 128) =
                    *(const u16x8*)(VT + ((size_t)h * DKV + row) * SEQ + kv0 + c8 * 8);
            }
        }
        __syncthreads();

        // S^T = K * Q^T : s[kt] holds S[kv=(r&3)+8*(r>>2)+4*hi + 32*kt][q=c]
        f32x16 s[2] = {};
        __builtin_amdgcn_s_setprio(1);
#pragma unroll
        for (int kt = 0; kt < 2; ++kt) {
#pragma unroll
            for (int dc = 0; dc < 8; ++dc) {
                u16x8 kh = *(u16x8*)ldsp(sKh, kt * 32 + c, dc * 32 + hi * 16, 256);
                u16x8 kl = *(u16x8*)ldsp(sKl, kt * 32 + c, dc * 32 + hi * 16, 256);
                s[kt] = mfma32(kh, qh[dc], s[kt]);
                s[kt] = mfma32(kl, qh[dc], s[kt]);
                s[kt] = mfma32(kh, ql[dc], s[kt]);
            }
        }
        __builtin_amdgcn_s_setprio(0);

        // online softmax — lane-local row reduce + one cross-half exchange
        float vmax = s[0][0];
#pragma unroll
        for (int r = 1; r < 16; ++r) vmax = fmaxf(vmax, s[0][r]);
#pragma unroll
        for (int r = 0; r < 16; ++r) vmax = fmaxf(vmax, s[1][r]);
        vmax = fmaxf(vmax, __shfl_xor(vmax, 32));
        float mnew = fmaxf(mrun, vmax);
        float corr = __expf(mrun - mnew);
        mrun = mnew;
        float rs = 0.f;
#pragma unroll
        for (int kt = 0; kt < 2; ++kt)
#pragma unroll
            for (int r = 0; r < 16; ++r) {
                float p = __expf(s[kt][r] - mnew);
                s[kt][r] = p;
                rs += p;
            }
        rs += __shfl_xor(rs, 32);
        lrun = lrun * corr + rs;
#pragma unroll
        for (int vt = 0; vt < 4; ++vt)
#pragma unroll
            for (int r = 0; r < 16; ++r) o[vt][r] *= corr;

        // P -> B-frag (in-register) and PV: O^T += V^T · P^T
#pragma unroll
        for (int kt = 0; kt < 2; ++kt) {
            unsigned wv[8], xw[8];
#pragma unroll
            for (int i = 0; i < 8; ++i) wv[i] = cvtpk(s[kt][2 * i], s[kt][2 * i + 1]);
#pragma unroll
            for (int i = 0; i < 8; ++i) xw[i] = (unsigned)__shfl_xor((int)wv[i], 32);
            __builtin_amdgcn_s_setprio(1);
#pragma unroll
            for (int kc = 0; kc < 2; ++kc) {
                u32x4 pw;
                pw[0] = hi ? xw[4 * kc + 2] : wv[4 * kc + 0];
                pw[1] = hi ? xw[4 * kc + 3] : wv[4 * kc + 1];
                pw[2] = hi ? wv[4 * kc + 2] : xw[4 * kc + 0];
                pw[3] = hi ? wv[4 * kc + 3] : xw[4 * kc + 1];
                u16x8 pf = __builtin_bit_cast(u16x8, pw);
#pragma unroll
                for (int vt = 0; vt < 4; ++vt) {
                    u16x8 vf = *(u16x8*)ldsp(sV, vt * 32 + c, kt * 64 + kc * 32 + hi * 16, 128);
                    o[vt] = mfma32(vf, pf, o[vt]);
                }
            }
            __builtin_amdgcn_s_setprio(0);
        }
    }

    float inv = 1.0f / lrun;
#pragma unroll
    for (int vt = 0; vt < 4; ++vt)
#pragma unroll
        for (int rg = 0; rg < 4; ++rg) {
            u16x4 pv;
#pragma unroll
            for (int j = 0; j < 4; ++j) pv[j] = f2bf(o[vt][rg * 4 + j] * inv);
            *(u16x4*)(Abuf + (size_t)qrow * (NH * DKV) + h * DKV + vt * 32 + rg * 8 + hi * 4) = pv;
        }
}

// ---------------------------------------------------------------------------
// Final GEMM: out f32 [SEQ][DA] = Abuf bf16 [SEQ][2048] @ W (via WT bf16 [d][j])
// ---------------------------------------------------------------------------
__global__ void __launch_bounds__(256) gemm_out_k(const u16* __restrict__ Abuf,
                                                  const u16* __restrict__ WT,
                                                  float* __restrict__ out) {
    __shared__ u16 sA[128 * 64];
    __shared__ u16 sB[128 * 64];
    int t = threadIdx.x, lane = t & 63, w = t >> 6, wr = w >> 1, wc = w & 1;
    int g = lane >> 4, c = lane & 15;
    int bm0 = blockIdx.x * 128, bn0 = blockIdx.y * 128;
    f32x4 acc[4][4] = {};

    for (int k0 = 0; k0 < DA; k0 += 64) {
        __syncthreads();
        for (int i = 0; i < 4; ++i) {
            int idx = t + i * 256, row = idx >> 3, c8 = idx & 7;
            *(u16x8*)ldsp(sA, row, c8 * 16, 128) =
                *(const u16x8*)(Abuf + (size_t)(bm0 + row) * DA + k0 + c8 * 8);
            *(u16x8*)ldsp(sB, row, c8 * 16, 128) =
                *(const u16x8*)(WT + (size_t)(bn0 + row) * DA + k0 + c8 * 8);
        }
        __syncthreads();
        for (int kc = 0; kc < 2; ++kc) {
            int kb = (kc * 32 + g * 8) * 2;
            u16x8 af[4], bfq[4];
            for (int m = 0; m < 4; ++m) af[m]  = *(u16x8*)ldsp(sA, wr * 64 + m * 16 + c, kb, 128);
            for (int n = 0; n < 4; ++n) bfq[n] = *(u16x8*)ldsp(sB, wc * 64 + n * 16 + c, kb, 128);
            for (int m = 0; m < 4; ++m)
                for (int n = 0; n < 4; ++n)
                    acc[m][n] = mfma16(af[m], bfq[n], acc[m][n]);
        }
    }
    for (int m = 0; m < 4; ++m)
        for (int n = 0; n < 4; ++n) {
            int row0 = bm0 + wr * 64 + m * 16 + g * 4;
            int col  = bn0 + wc * 64 + n * 16 + c;
            for (int j = 0; j < 4; ++j)
                out[(size_t)(row0 + j) * DA + col] = acc[m][n][j];
        }
}

// ---------------------------------------------------------------------------
extern "C" void kernel_launch(void* const* d_in, const int* in_sizes, int n_in,
                              void* d_out, int out_size, void* d_ws, size_t ws_size,
                              hipStream_t stream) {
    const float* queries = (const float*)d_in[0];
    const float* keys    = (const float*)d_in[1];
    const float* values  = (const float*)d_in[2];
    const float* Eq      = (const float*)d_in[3];
    const float* Ek      = (const float*)d_in[4];
    const float* Ev      = (const float*)d_in[5];
    const float* Wout    = (const float*)d_in[6];
    float* out = (float*)d_out;

    const size_t PROJ = (size_t)NH * SEQ * DKV;   // 8,388,608 elems
    const size_t TSZ  = (size_t)DA * DA;          // 4,194,304 elems
    u16* p  = (u16*)d_ws;
    u16* QH = p; p += PROJ;
    u16* QL = p; p += PROJ;
    u16* KH = p; p += PROJ;
    u16* KL = p; p += PROJ;
    u16* VT = p; p += PROJ;
    u16* AB = p; p += (size_t)SEQ * NH * DKV;
    u16* TH = p; p += TSZ;
    u16* TL = p; p += TSZ;

    dim3 tgE(DA / 32, DKV / 32, NH);   // E transposes
    dim3 tgW(DA / 32, DA / 32, 1);     // W transpose
    dim3 pg(SEQ / 128, NH);

    transpose_split_k<<<tgE, 256, 0, stream>>>(Eq, TH, TL, DA, DKV);
    proj_k<2><<<pg, 256, 0, stream>>>(queries, TH, TL, QH, QL);
    transpose_split_k<<<tgE, 256, 0, stream>>>(Ek, TH, TL, DA, DKV);
    proj_k<1><<<pg, 256, 0, stream>>>(keys, TH, TL, KH, KL);
    transpose_split_k<<<tgE, 256, 0, stream>>>(Ev, TH, nullptr, DA, DKV);
    proj_k<0><<<pg, 256, 0, stream>>>(values, TH, nullptr, VT, nullptr);
    transpose_split_k<<<tgW, 256, 0, stream>>>(Wout, TH, nullptr, DA, DA);
    attn_k<<<dim3(SEQ / 128, NH), 256, 0, stream>>>(QH, QL, KH, KL, VT, AB);
    gemm_out_k<<<dim3(SEQ / 128, DA / 128), 256, 0, stream>>>(AB, TH, out);
}